// Round 19
// baseline (97.655 us; speedup 1.0000x reference)
//
#include <hip/hip_runtime.h>

typedef __attribute__((ext_vector_type(8))) short bf16x8;
typedef __attribute__((ext_vector_type(4))) float f32x4;
typedef __attribute__((ext_vector_type(2))) long long2v;
typedef __attribute__((ext_vector_type(8))) int i32x8;
typedef unsigned int u32;
typedef unsigned long long u64;

#define LOG2E 1.44269504088896f

__device__ __forceinline__ short f2bf(float f) {
    union { float f; unsigned u; } v; v.f = f;
    unsigned r = v.u + 0x7fffu + ((v.u >> 16) & 1u);
    return (short)(r >> 16);
}

#if __has_builtin(__builtin_amdgcn_cvt_pk_fp8_f32)
// HW packed f32->fp8 (OCP e4m3fn on gfx950, RNE, saturating): 4 instrs per 8 floats
__device__ __forceinline__ long pack8_e4m3(float4 a, float4 b) {
    int lo = 0, hi = 0;
    lo = __builtin_amdgcn_cvt_pk_fp8_f32(a.x, a.y, lo, false);
    lo = __builtin_amdgcn_cvt_pk_fp8_f32(a.z, a.w, lo, true);
    hi = __builtin_amdgcn_cvt_pk_fp8_f32(b.x, b.y, hi, false);
    hi = __builtin_amdgcn_cvt_pk_fp8_f32(b.z, b.w, hi, true);
    return (long)(((u64)(u32)hi << 32) | (u32)lo);
}
#else
// software fallback (r17-verified): RNE, saturate to 448, subnormals
__device__ __forceinline__ u32 f2e4m3(float f) {
    u32 u = __float_as_uint(f);
    u32 sgn = (u >> 24) & 0x80u;
    u32 mag = u & 0x7fffffffu;
    if (mag >= 0x43E00000u) return sgn | 0x7Eu;
    if (mag < 0x3C800000u) {
        u32 q = (u32)(__uint_as_float(mag) * 512.0f + 0.5f);
        return sgn | q;
    }
    u32 r = mag + 0x0007FFFFu + ((mag >> 20) & 1u);
    u32 e8 = ((r >> 23) - 120u) & 0xFu;
    u32 m3 = (r >> 20) & 7u;
    return sgn | (e8 << 3) | m3;
}
__device__ __forceinline__ long pack8_e4m3(float4 a, float4 b) {
    u32 lo = f2e4m3(a.x) | (f2e4m3(a.y) << 8) | (f2e4m3(a.z) << 16) | (f2e4m3(a.w) << 24);
    u32 hi = f2e4m3(b.x) | (f2e4m3(b.y) << 8) | (f2e4m3(b.z) << 16) | (f2e4m3(b.w) << 24);
    return (long)(((u64)hi << 32) | lo);
}
#endif

#if __has_builtin(__builtin_amdgcn_exp2f)
#define EXP2(x) __builtin_amdgcn_exp2f(x)
#else
#define EXP2(x) __builtin_exp2f(x)
#endif

__device__ __forceinline__ u32 pack_bf16_trunc(float lo, float hi) {
#if __has_builtin(__builtin_amdgcn_perm)
    return __builtin_amdgcn_perm(__float_as_uint(hi), __float_as_uint(lo), 0x07060302u);
#else
    return (__float_as_uint(hi) & 0xFFFF0000u) | (__float_as_uint(lo) >> 16);
#endif
}

__device__ __forceinline__ void gload16(const void* g, void* l) {
    __builtin_amdgcn_global_load_lds(
        (const __attribute__((address_space(1))) void*)g,
        (__attribute__((address_space(3))) void*)l, 16, 0, 0);
}

// K=128 fp8 MFMA: scaled (identity e8m0 scales = 0x7F -> 2^0, layout-proof) with
// fallback to 4x K=32 on the SAME data (A/B k-conventions are self-consistent).
#if __has_builtin(__builtin_amdgcn_mfma_scale_f32_16x16x128_f8f6f4)
#define MFMA128(A, B, C) \
    C = __builtin_amdgcn_mfma_scale_f32_16x16x128_f8f6f4((A), (B), (C), 0, 0, 0, 0x7F7F7F7F, 0, 0x7F7F7F7F)
#else
#define MFMA128(A, B, C) do {                                                      \
        union { i32x8 v; long l[4]; } _a, _b; _a.v = (A); _b.v = (B);              \
        _Pragma("unroll")                                                          \
        for (int _dp = 0; _dp < 4; ++_dp)                                          \
            C = __builtin_amdgcn_mfma_f32_16x16x32_fp8_fp8(_a.l[_dp], _b.l[_dp], (C), 0, 0, 0); \
    } while (0)
#endif

// ---------------- prep (r17 layouts; conversion now HW cvt_pk) ----------------
// bid 0..255  : 2-fold tables, permuted slot ((c*2+h)*4+g)*4+j for center
//               m = c*32+8g+4h+j: nscs=-s*||c||^2*L, ts=2s*L
// bid 256..319: centers -> cfrag8 for K=128 operands (16B slots, r17 layout)
// bid 320..383: W -> wfrag (bf16) PV B-frag [c][ot][lane]
__global__ __launch_bounds__(256) void rbf_prep(
    const float* __restrict__ centers, const float* __restrict__ sigmas,
    const float* __restrict__ W,
    char* __restrict__ cfrag8, short* __restrict__ wfrag,
    float* __restrict__ nscsp, float* __restrict__ tsp)
{
    const int tid = threadIdx.x;
    const int bid = blockIdx.x;
    if (bid < 256) {
        const int lane = tid & 63, w = tid >> 6;
        const int m = bid * 4 + w;
        const float4 v = ((const float4*)(centers + (size_t)m * 256))[lane];
        float s = v.x*v.x + v.y*v.y + v.z*v.z + v.w*v.w;
        #pragma unroll
        for (int off = 32; off >= 1; off >>= 1) s += __shfl_xor(s, off, 64);
        if (lane == 0) {
            const float sg = sigmas[m];
            const int c = m >> 5, w5 = m & 31;
            const int g = w5 >> 3, r = w5 & 7, h = r >> 2, j = r & 3;
            const int slot = ((c * 2 + h) * 4 + g) * 4 + j;
            nscsp[slot] = -sg * s * LOG2E;
            tsp[slot]   = 2.0f * sg * LOG2E;
        }
    } else if (bid < 320) {
        const int s = (bid - 256) * 256 + tid;               // 0..16383 (16B slots)
        const int c = s >> 9, h2k = (s >> 7) & 3, piece = (s >> 6) & 1, lane = s & 63;
        const int h = h2k >> 1, ks = h2k & 1;
        const int l15 = lane & 15, g4 = lane >> 4;
        const int m = c * 32 + 8 * (l15 >> 2) + 4 * h + (l15 & 3);
        const int kb = ks * 128 + g4 * 32 + piece * 16;
        const float* cp = centers + (size_t)m * 256 + kb;
        const float4 a0 = *(const float4*)(cp);
        const float4 a1 = *(const float4*)(cp + 4);
        const float4 a2 = *(const float4*)(cp + 8);
        const float4 a3 = *(const float4*)(cp + 12);
        long2v t;
        t[0] = pack8_e4m3(a0, a1);
        t[1] = pack8_e4m3(a2, a3);
        *(long2v*)(cfrag8 + (size_t)s * 16) = t;
    } else {
        const int s = (bid - 320) * 256 + tid;               // 0..16383
        const int c = s >> 9, ot = (s >> 6) & 7, lane = s & 63;
        const int o = ot * 16 + (lane & 15);
        const int k = c * 32 + (lane >> 4) * 8;
        const float4 a = *(const float4*)(W + (size_t)o * 1024 + k);
        const float4 b = *(const float4*)(W + (size_t)o * 1024 + k + 4);
        bf16x8 t;
        t[0]=f2bf(a.x); t[1]=f2bf(a.y); t[2]=f2bf(a.z); t[3]=f2bf(a.w);
        t[4]=f2bf(b.x); t[5]=f2bf(b.y); t[6]=f2bf(b.z); t[7]=f2bf(b.w);
        ((bf16x8*)wfrag)[s] = t;
    }
}

// ---------------- main: r17 skeleton + HW fp8 convert + acc-init hxs fold ----------------
// 512 blocks x 256 threads (4 fat waves, 32 rows/wave), 2 blocks/CU, ring-4 C +
// tables (40 KB). Per chunk: W(c)->regs (VMEM), STAGE(c+3) (DMA), S via
// 2x ds_read_b128-pairs + 8 scaled K=128 MFMAs (C-init = -xs/2, so exp arg is
// a single fmaf), exp/pack, PV. Counted vmcnt guard only; one barrier/chunk.
__global__ __launch_bounds__(256, 2) void rbf_main(
    const float* __restrict__ x, const float* __restrict__ bvec,
    const char* __restrict__ cfrag8, const short* __restrict__ wfrag,
    const float* __restrict__ nscsp, const float* __restrict__ tsp,
    float* __restrict__ out)
{
    __shared__ char   Cb8[4][8192];   // ring-4: chunk c -> slot c&3; [h2k][piece][lane]16B
    __shared__ float4 Tls[512];       // 8 KB: [0..255]=nscs, [256..511]=ts (permuted)

    const int tid = threadIdx.x;
    const int lane = tid & 63;
    const int l15 = lane & 15;
    const int g4 = lane >> 4;
    const int w = tid >> 6;                    // 0..3
    const int qb = blockIdx.x * 128 + w * 32;  // 32 rows per wave (2x 16-row tiles)

#define STAGE(ci, slot) do {                                                       \
        const char* _cs = cfrag8 + (size_t)(ci) * 8192 + w * 2048 + lane * 16;     \
        gload16(_cs,        &Cb8[(slot)][w * 2048]);                               \
        gload16(_cs + 1024, &Cb8[(slot)][w * 2048 + 1024]);                        \
    } while (0)

// S (K=128, C-init = -xs/2) + exp + pack; math identical to r17 (sub folded into init)
#define SEXPR(slot, cc, pa0, pa1) do {                                             \
        const char* cb = &Cb8[(slot)][0] + (size_t)lane * 16;                      \
        union { long2v p[2]; i32x8 v; } A0, A1, A2, A3;                            \
        A0.p[0] = *(const long2v*)(cb);          A0.p[1] = *(const long2v*)(cb + 1024); \
        A1.p[0] = *(const long2v*)(cb + 2048);   A1.p[1] = *(const long2v*)(cb + 3072); \
        A2.p[0] = *(const long2v*)(cb + 4096);   A2.p[1] = *(const long2v*)(cb + 5120); \
        A3.p[0] = *(const long2v*)(cb + 6144);   A3.p[1] = *(const long2v*)(cb + 7168); \
        f32x4 s00 = nh0, s01 = nh0, s10 = nh1, s11 = nh1;                          \
        MFMA128(A0.v, xq00, s00);  MFMA128(A0.v, xq10, s10);                       \
        MFMA128(A1.v, xq01, s00);  MFMA128(A1.v, xq11, s10);                       \
        MFMA128(A2.v, xq00, s01);  MFMA128(A2.v, xq10, s11);                       \
        MFMA128(A3.v, xq01, s01);  MFMA128(A3.v, xq11, s11);                       \
        const int base0 = ((cc) * 2 + 0) * 4 + g4;                                 \
        const int base1 = ((cc) * 2 + 1) * 4 + g4;                                 \
        const float4 q0 = Tls[base0];                                              \
        const float4 t0 = Tls[256 + base0];                                        \
        const float4 q1 = Tls[base1];                                              \
        const float4 t1 = Tls[256 + base1];                                        \
        const float* q0p = (const float*)&q0; const float* t0p = (const float*)&t0;\
        const float* q1p = (const float*)&q1; const float* t1p = (const float*)&t1;\
        float p00[4], p01[4], p10[4], p11[4];                                      \
        _Pragma("unroll")                                                          \
        for (int j = 0; j < 4; ++j) {                                              \
            p00[j] = EXP2(fmaf(t0p[j], s00[j], q0p[j]));                           \
            p01[j] = EXP2(fmaf(t1p[j], s01[j], q1p[j]));                           \
            p10[j] = EXP2(fmaf(t0p[j], s10[j], q0p[j]));                           \
            p11[j] = EXP2(fmaf(t1p[j], s11[j], q1p[j]));                           \
        }                                                                          \
        pa0.u[0] = pack_bf16_trunc(p00[0], p00[1]);                                \
        pa0.u[1] = pack_bf16_trunc(p00[2], p00[3]);                                \
        pa0.u[2] = pack_bf16_trunc(p01[0], p01[1]);                                \
        pa0.u[3] = pack_bf16_trunc(p01[2], p01[3]);                                \
        pa1.u[0] = pack_bf16_trunc(p10[0], p10[1]);                                \
        pa1.u[1] = pack_bf16_trunc(p10[2], p10[3]);                                \
        pa1.u[2] = pack_bf16_trunc(p11[0], p11[1]);                                \
        pa1.u[3] = pack_bf16_trunc(p11[2], p11[3]);                                \
    } while (0)

#define PVX(pa0, pa1, wv) do {                                                     \
        _Pragma("unroll")                                                          \
        for (int ot = 0; ot < 8; ++ot) {                                           \
            acc[0][ot] = __builtin_amdgcn_mfma_f32_16x16x32_bf16(pa0.v, wv[ot], acc[0][ot], 0, 0, 0); \
            acc[1][ot] = __builtin_amdgcn_mfma_f32_16x16x32_bf16(pa1.v, wv[ot], acc[1][ot], 0, 0, 0); \
        }                                                                          \
    } while (0)

    // ---- prologue: stage chunks 0..2; tables -> LDS; X -> fp8 K=128 operands ----
    STAGE(0, 0);
    STAGE(1, 1);
    STAGE(2, 2);

    Tls[tid]       = ((const float4*)nscsp)[tid];
    Tls[256 + tid] = ((const float4*)tsp)[tid];

    i32x8 xq00, xq01, xq10, xq11;   // [tile][kslice]
    float xs[2];
    #pragma unroll
    for (int t = 0; t < 2; ++t) {
        const float* xr = x + (size_t)(qb + t * 16 + l15) * 256;
        float ss = 0.f;
        #pragma unroll
        for (int ks = 0; ks < 2; ++ks) {
            union { long lg[4]; i32x8 v; } xx;
            const float* xb = xr + ks * 128 + g4 * 32;
            #pragma unroll
            for (int q8 = 0; q8 < 4; ++q8) {
                const float4 a = *(const float4*)(xb + q8 * 8);
                const float4 b = *(const float4*)(xb + q8 * 8 + 4);
                ss += a.x*a.x + a.y*a.y + a.z*a.z + a.w*a.w
                    + b.x*b.x + b.y*b.y + b.z*b.z + b.w*b.w;
                xx.lg[q8] = pack8_e4m3(a, b);
            }
            if (t == 0) { if (ks == 0) xq00 = xx.v; else xq01 = xx.v; }
            else        { if (ks == 0) xq10 = xx.v; else xq11 = xx.v; }
        }
        ss += __shfl_xor(ss, 16, 64);
        ss += __shfl_xor(ss, 32, 64);
        xs[t] = ss;
    }
    const float hxs0 = 0.5f * xs[0];
    const float hxs1 = 0.5f * xs[1];
    const f32x4 nh0 = (f32x4){-hxs0, -hxs0, -hxs0, -hxs0};
    const f32x4 nh1 = (f32x4){-hxs1, -hxs1, -hxs1, -hxs1};

    f32x4 acc[2][8];
    #pragma unroll
    for (int t = 0; t < 2; ++t)
        #pragma unroll
        for (int ot = 0; ot < 8; ++ot) acc[t][ot] = (f32x4){0.f, 0.f, 0.f, 0.f};

    __syncthreads();   // prologue drain: chunks 0-2 DMA + tables + X

    const bf16x8* wsrc = (const bf16x8*)wfrag + lane;

    for (int c = 0; c < 32; ++c) {
        const int slot = c & 3;

        // W(c) -> regs first (older than STAGE in vmcnt order: compiler's W-wait
        // leaves the newer STAGE outstanding; prior iters' STAGEs retire with it)
        bf16x8 wv[8];
        #pragma unroll
        for (int f = 0; f < 8; ++f) wv[f] = wsrc[(size_t)c * 512 + f * 64];

        if (c <= 28) STAGE(c + 3, (c + 3) & 3);

        union { u32 u[4]; bf16x8 v; } pa0, pa1;
        SEXPR(slot, c, pa0, pa1);
        PVX(pa0, pa1, wv);

        if (c < 31) {
            if (c <= 28) { asm volatile("s_waitcnt vmcnt(2)" ::: "memory"); }
            else         { asm volatile("s_waitcnt vmcnt(0)" ::: "memory"); }
            __builtin_amdgcn_s_barrier();
        }
    }

    // ---- epilogue: D layout col=l15 (o-sub), row=g4*4+jr (q-sub) ----
    #pragma unroll
    for (int t = 0; t < 2; ++t) {
        #pragma unroll
        for (int jr = 0; jr < 4; ++jr) {
            const int q = qb + t * 16 + g4 * 4 + jr;
            #pragma unroll
            for (int ot = 0; ot < 8; ++ot)
                out[(size_t)q * 128 + ot * 16 + l15] = acc[t][ot][jr] + bvec[ot * 16 + l15];
        }
    }
#undef STAGE
#undef SEXPR
#undef PVX
}

extern "C" void kernel_launch(void* const* d_in, const int* in_sizes, int n_in,
                              void* d_out, int out_size, void* d_ws, size_t ws_size,
                              hipStream_t stream) {
    (void)in_sizes; (void)n_in; (void)out_size; (void)ws_size;
    const float* x       = (const float*)d_in[0];
    const float* centers = (const float*)d_in[1];
    const float* sigmas  = (const float*)d_in[2];
    const float* W       = (const float*)d_in[3];
    const float* b       = (const float*)d_in[4];
    float* out = (float*)d_out;

    char*  cfrag8 = (char*)d_ws;                     // 16384 slots * 16B = 256 KB
    short* wfrag  = (short*)(cfrag8 + 16384 * 16);   // 16384 slots * 16B = 256 KB
    float* nscsp  = (float*)(wfrag + 16384 * 8);     // 4 KB
    float* tsp    = nscsp + 1024;                    // 4 KB

    rbf_prep<<<384, 256, 0, stream>>>(centers, sigmas, W, cfrag8, wfrag, nscsp, tsp);
    rbf_main<<<512, 256, 0, stream>>>(x, b, cfrag8, wfrag, nscsp, tsp, out);
}

// Round 20
// 71.968 us; speedup vs baseline: 1.3569x; 1.3569x over previous
//
#include <hip/hip_runtime.h>

typedef __attribute__((ext_vector_type(8))) short bf16x8;
typedef __attribute__((ext_vector_type(4))) float f32x4;
typedef __attribute__((ext_vector_type(2))) long long2v;
typedef __attribute__((ext_vector_type(8))) int i32x8;
typedef unsigned int u32;
typedef unsigned long long u64;

#define LOG2E 1.44269504088896f

__device__ __forceinline__ short f2bf(float f) {
    union { float f; unsigned u; } v; v.f = f;
    unsigned r = v.u + 0x7fffu + ((v.u >> 16) & 1u);
    return (short)(r >> 16);
}

#if __has_builtin(__builtin_amdgcn_cvt_pk_fp8_f32)
// HW packed f32->fp8 (OCP e4m3fn on gfx950, RNE, saturating): 4 instrs per 8 floats
// [r19: VALUBusy 17.5->11.7 confirmed this binds and computes correctly (absmax 0.0)]
__device__ __forceinline__ long pack8_e4m3(float4 a, float4 b) {
    int lo = 0, hi = 0;
    lo = __builtin_amdgcn_cvt_pk_fp8_f32(a.x, a.y, lo, false);
    lo = __builtin_amdgcn_cvt_pk_fp8_f32(a.z, a.w, lo, true);
    hi = __builtin_amdgcn_cvt_pk_fp8_f32(b.x, b.y, hi, false);
    hi = __builtin_amdgcn_cvt_pk_fp8_f32(b.z, b.w, hi, true);
    return (long)(((u64)(u32)hi << 32) | (u32)lo);
}
#else
// software fallback (r17-verified): RNE, saturate to 448, subnormals
__device__ __forceinline__ u32 f2e4m3(float f) {
    u32 u = __float_as_uint(f);
    u32 sgn = (u >> 24) & 0x80u;
    u32 mag = u & 0x7fffffffu;
    if (mag >= 0x43E00000u) return sgn | 0x7Eu;
    if (mag < 0x3C800000u) {
        u32 q = (u32)(__uint_as_float(mag) * 512.0f + 0.5f);
        return sgn | q;
    }
    u32 r = mag + 0x0007FFFFu + ((mag >> 20) & 1u);
    u32 e8 = ((r >> 23) - 120u) & 0xFu;
    u32 m3 = (r >> 20) & 7u;
    return sgn | (e8 << 3) | m3;
}
__device__ __forceinline__ long pack8_e4m3(float4 a, float4 b) {
    u32 lo = f2e4m3(a.x) | (f2e4m3(a.y) << 8) | (f2e4m3(a.z) << 16) | (f2e4m3(a.w) << 24);
    u32 hi = f2e4m3(b.x) | (f2e4m3(b.y) << 8) | (f2e4m3(b.z) << 16) | (f2e4m3(b.w) << 24);
    return (long)(((u64)hi << 32) | lo);
}
#endif

#if __has_builtin(__builtin_amdgcn_exp2f)
#define EXP2(x) __builtin_amdgcn_exp2f(x)
#else
#define EXP2(x) __builtin_exp2f(x)
#endif

__device__ __forceinline__ u32 pack_bf16_trunc(float lo, float hi) {
#if __has_builtin(__builtin_amdgcn_perm)
    return __builtin_amdgcn_perm(__float_as_uint(hi), __float_as_uint(lo), 0x07060302u);
#else
    return (__float_as_uint(hi) & 0xFFFF0000u) | (__float_as_uint(lo) >> 16);
#endif
}

__device__ __forceinline__ void gload16(const void* g, void* l) {
    __builtin_amdgcn_global_load_lds(
        (const __attribute__((address_space(1))) void*)g,
        (__attribute__((address_space(3))) void*)l, 16, 0, 0);
}

// K=128 fp8 MFMA: scaled (identity e8m0 scales = 0x7F -> 2^0, layout-proof) with
// fallback to 4x K=32 on the SAME data (A/B k-conventions are self-consistent).
#if __has_builtin(__builtin_amdgcn_mfma_scale_f32_16x16x128_f8f6f4)
#define MFMA128(A, B, C) \
    C = __builtin_amdgcn_mfma_scale_f32_16x16x128_f8f6f4((A), (B), (C), 0, 0, 0, 0x7F7F7F7F, 0, 0x7F7F7F7F)
#else
#define MFMA128(A, B, C) do {                                                      \
        union { i32x8 v; long l[4]; } _a, _b; _a.v = (A); _b.v = (B);              \
        _Pragma("unroll")                                                          \
        for (int _dp = 0; _dp < 4; ++_dp)                                          \
            C = __builtin_amdgcn_mfma_f32_16x16x32_fp8_fp8(_a.l[_dp], _b.l[_dp], (C), 0, 0, 0); \
    } while (0)
#endif

// ---------------- prep (r17 layouts; conversion via pack8_e4m3 above) ----------------
// bid 0..255  : 2-fold tables, permuted slot ((c*2+h)*4+g)*4+j for center
//               m = c*32+8g+4h+j: nscs=-s*||c||^2*L, ts=2s*L
// bid 256..319: centers -> cfrag8 for K=128 operands (16B slots, r17 layout)
// bid 320..383: W -> wfrag (bf16) PV B-frag [c][ot][lane]
__global__ __launch_bounds__(256) void rbf_prep(
    const float* __restrict__ centers, const float* __restrict__ sigmas,
    const float* __restrict__ W,
    char* __restrict__ cfrag8, short* __restrict__ wfrag,
    float* __restrict__ nscsp, float* __restrict__ tsp)
{
    const int tid = threadIdx.x;
    const int bid = blockIdx.x;
    if (bid < 256) {
        const int lane = tid & 63, w = tid >> 6;
        const int m = bid * 4 + w;
        const float4 v = ((const float4*)(centers + (size_t)m * 256))[lane];
        float s = v.x*v.x + v.y*v.y + v.z*v.z + v.w*v.w;
        #pragma unroll
        for (int off = 32; off >= 1; off >>= 1) s += __shfl_xor(s, off, 64);
        if (lane == 0) {
            const float sg = sigmas[m];
            const int c = m >> 5, w5 = m & 31;
            const int g = w5 >> 3, r = w5 & 7, h = r >> 2, j = r & 3;
            const int slot = ((c * 2 + h) * 4 + g) * 4 + j;
            nscsp[slot] = -sg * s * LOG2E;
            tsp[slot]   = 2.0f * sg * LOG2E;
        }
    } else if (bid < 320) {
        const int s = (bid - 256) * 256 + tid;               // 0..16383 (16B slots)
        const int c = s >> 9, h2k = (s >> 7) & 3, piece = (s >> 6) & 1, lane = s & 63;
        const int h = h2k >> 1, ks = h2k & 1;
        const int l15 = lane & 15, g4 = lane >> 4;
        const int m = c * 32 + 8 * (l15 >> 2) + 4 * h + (l15 & 3);
        const int kb = ks * 128 + g4 * 32 + piece * 16;
        const float* cp = centers + (size_t)m * 256 + kb;
        const float4 a0 = *(const float4*)(cp);
        const float4 a1 = *(const float4*)(cp + 4);
        const float4 a2 = *(const float4*)(cp + 8);
        const float4 a3 = *(const float4*)(cp + 12);
        long2v t;
        t[0] = pack8_e4m3(a0, a1);
        t[1] = pack8_e4m3(a2, a3);
        *(long2v*)(cfrag8 + (size_t)s * 16) = t;
    } else {
        const int s = (bid - 320) * 256 + tid;               // 0..16383
        const int c = s >> 9, ot = (s >> 6) & 7, lane = s & 63;
        const int o = ot * 16 + (lane & 15);
        const int k = c * 32 + (lane >> 4) * 8;
        const float4 a = *(const float4*)(W + (size_t)o * 1024 + k);
        const float4 b = *(const float4*)(W + (size_t)o * 1024 + k + 4);
        bf16x8 t;
        t[0]=f2bf(a.x); t[1]=f2bf(a.y); t[2]=f2bf(a.z); t[3]=f2bf(a.w);
        t[4]=f2bf(b.x); t[5]=f2bf(b.y); t[6]=f2bf(b.z); t[7]=f2bf(b.w);
        ((bf16x8*)wfrag)[s] = t;
    }
}

// ---------------- main: r17 skeleton byte-identical (Z4 acc init, s - hxs in exp) ----------------
// 512 blocks x 256 threads (4 fat waves, 32 rows/wave), 2 blocks/CU, ring-4 C +
// tables (40 KB). Per chunk: W(c)->regs (VMEM), STAGE(c+3) (DMA), S via
// 2x ds_read_b128-pairs + 8 scaled K=128 MFMAs, exp/pack, PV. Counted vmcnt
// guard only; one barrier/chunk. [r19's acc-init fold REMOVED — suspect in the
// unexplained bench regression; this config differs from r17 (68.2us) only by
// the HW cvt_pk conversion.]
__global__ __launch_bounds__(256, 2) void rbf_main(
    const float* __restrict__ x, const float* __restrict__ bvec,
    const char* __restrict__ cfrag8, const short* __restrict__ wfrag,
    const float* __restrict__ nscsp, const float* __restrict__ tsp,
    float* __restrict__ out)
{
    __shared__ char   Cb8[4][8192];   // ring-4: chunk c -> slot c&3; [h2k][piece][lane]16B
    __shared__ float4 Tls[512];       // 8 KB: [0..255]=nscs, [256..511]=ts (permuted)

    const int tid = threadIdx.x;
    const int lane = tid & 63;
    const int l15 = lane & 15;
    const int g4 = lane >> 4;
    const int w = tid >> 6;                    // 0..3
    const int qb = blockIdx.x * 128 + w * 32;  // 32 rows per wave (2x 16-row tiles)

#define STAGE(ci, slot) do {                                                       \
        const char* _cs = cfrag8 + (size_t)(ci) * 8192 + w * 2048 + lane * 16;     \
        gload16(_cs,        &Cb8[(slot)][w * 2048]);                               \
        gload16(_cs + 1024, &Cb8[(slot)][w * 2048 + 1024]);                        \
    } while (0)

#define Z4 (f32x4){0.f,0.f,0.f,0.f}

// S (K=128) + exp + pack; math identical to r17's verified body
#define SEXPR(slot, cc, pa0, pa1) do {                                             \
        const char* cb = &Cb8[(slot)][0] + (size_t)lane * 16;                      \
        union { long2v p[2]; i32x8 v; } A0, A1, A2, A3;                            \
        A0.p[0] = *(const long2v*)(cb);          A0.p[1] = *(const long2v*)(cb + 1024); \
        A1.p[0] = *(const long2v*)(cb + 2048);   A1.p[1] = *(const long2v*)(cb + 3072); \
        A2.p[0] = *(const long2v*)(cb + 4096);   A2.p[1] = *(const long2v*)(cb + 5120); \
        A3.p[0] = *(const long2v*)(cb + 6144);   A3.p[1] = *(const long2v*)(cb + 7168); \
        f32x4 s00 = Z4, s01 = Z4, s10 = Z4, s11 = Z4;                              \
        MFMA128(A0.v, xq00, s00);  MFMA128(A0.v, xq10, s10);                       \
        MFMA128(A1.v, xq01, s00);  MFMA128(A1.v, xq11, s10);                       \
        MFMA128(A2.v, xq00, s01);  MFMA128(A2.v, xq10, s11);                       \
        MFMA128(A3.v, xq01, s01);  MFMA128(A3.v, xq11, s11);                       \
        const int base0 = ((cc) * 2 + 0) * 4 + g4;                                 \
        const int base1 = ((cc) * 2 + 1) * 4 + g4;                                 \
        const float4 q0 = Tls[base0];                                              \
        const float4 t0 = Tls[256 + base0];                                        \
        const float4 q1 = Tls[base1];                                              \
        const float4 t1 = Tls[256 + base1];                                        \
        const float* q0p = (const float*)&q0; const float* t0p = (const float*)&t0;\
        const float* q1p = (const float*)&q1; const float* t1p = (const float*)&t1;\
        float p00[4], p01[4], p10[4], p11[4];                                      \
        _Pragma("unroll")                                                          \
        for (int j = 0; j < 4; ++j) {                                              \
            p00[j] = EXP2(fmaf(t0p[j], s00[j] - hxs0, q0p[j]));                    \
            p01[j] = EXP2(fmaf(t1p[j], s01[j] - hxs0, q1p[j]));                    \
            p10[j] = EXP2(fmaf(t0p[j], s10[j] - hxs1, q0p[j]));                    \
            p11[j] = EXP2(fmaf(t1p[j], s11[j] - hxs1, q1p[j]));                    \
        }                                                                          \
        pa0.u[0] = pack_bf16_trunc(p00[0], p00[1]);                                \
        pa0.u[1] = pack_bf16_trunc(p00[2], p00[3]);                                \
        pa0.u[2] = pack_bf16_trunc(p01[0], p01[1]);                                \
        pa0.u[3] = pack_bf16_trunc(p01[2], p01[3]);                                \
        pa1.u[0] = pack_bf16_trunc(p10[0], p10[1]);                                \
        pa1.u[1] = pack_bf16_trunc(p10[2], p10[3]);                                \
        pa1.u[2] = pack_bf16_trunc(p11[0], p11[1]);                                \
        pa1.u[3] = pack_bf16_trunc(p11[2], p11[3]);                                \
    } while (0)

#define PVX(pa0, pa1, wv) do {                                                     \
        _Pragma("unroll")                                                          \
        for (int ot = 0; ot < 8; ++ot) {                                           \
            acc[0][ot] = __builtin_amdgcn_mfma_f32_16x16x32_bf16(pa0.v, wv[ot], acc[0][ot], 0, 0, 0); \
            acc[1][ot] = __builtin_amdgcn_mfma_f32_16x16x32_bf16(pa1.v, wv[ot], acc[1][ot], 0, 0, 0); \
        }                                                                          \
    } while (0)

    // ---- prologue: stage chunks 0..2; tables -> LDS; X -> fp8 K=128 operands ----
    STAGE(0, 0);
    STAGE(1, 1);
    STAGE(2, 2);

    Tls[tid]       = ((const float4*)nscsp)[tid];
    Tls[256 + tid] = ((const float4*)tsp)[tid];

    i32x8 xq00, xq01, xq10, xq11;   // [tile][kslice]
    float xs[2];
    #pragma unroll
    for (int t = 0; t < 2; ++t) {
        const float* xr = x + (size_t)(qb + t * 16 + l15) * 256;
        float ss = 0.f;
        #pragma unroll
        for (int ks = 0; ks < 2; ++ks) {
            union { long lg[4]; i32x8 v; } xx;
            const float* xb = xr + ks * 128 + g4 * 32;
            #pragma unroll
            for (int q8 = 0; q8 < 4; ++q8) {
                const float4 a = *(const float4*)(xb + q8 * 8);
                const float4 b = *(const float4*)(xb + q8 * 8 + 4);
                ss += a.x*a.x + a.y*a.y + a.z*a.z + a.w*a.w
                    + b.x*b.x + b.y*b.y + b.z*b.z + b.w*b.w;
                xx.lg[q8] = pack8_e4m3(a, b);
            }
            if (t == 0) { if (ks == 0) xq00 = xx.v; else xq01 = xx.v; }
            else        { if (ks == 0) xq10 = xx.v; else xq11 = xx.v; }
        }
        ss += __shfl_xor(ss, 16, 64);
        ss += __shfl_xor(ss, 32, 64);
        xs[t] = ss;
    }
    const float hxs0 = 0.5f * xs[0];
    const float hxs1 = 0.5f * xs[1];

    f32x4 acc[2][8];
    #pragma unroll
    for (int t = 0; t < 2; ++t)
        #pragma unroll
        for (int ot = 0; ot < 8; ++ot) acc[t][ot] = Z4;

    __syncthreads();   // prologue drain: chunks 0-2 DMA + tables + X

    const bf16x8* wsrc = (const bf16x8*)wfrag + lane;

    for (int c = 0; c < 32; ++c) {
        const int slot = c & 3;

        // W(c) -> regs first (older than STAGE in vmcnt order: compiler's W-wait
        // leaves the newer STAGE outstanding; prior iters' STAGEs retire with it)
        bf16x8 wv[8];
        #pragma unroll
        for (int f = 0; f < 8; ++f) wv[f] = wsrc[(size_t)c * 512 + f * 64];

        if (c <= 28) STAGE(c + 3, (c + 3) & 3);

        union { u32 u[4]; bf16x8 v; } pa0, pa1;
        SEXPR(slot, c, pa0, pa1);
        PVX(pa0, pa1, wv);

        if (c < 31) {
            if (c <= 28) { asm volatile("s_waitcnt vmcnt(2)" ::: "memory"); }
            else         { asm volatile("s_waitcnt vmcnt(0)" ::: "memory"); }
            __builtin_amdgcn_s_barrier();
        }
    }

    // ---- epilogue: D layout col=l15 (o-sub), row=g4*4+jr (q-sub) ----
    #pragma unroll
    for (int t = 0; t < 2; ++t) {
        #pragma unroll
        for (int jr = 0; jr < 4; ++jr) {
            const int q = qb + t * 16 + g4 * 4 + jr;
            #pragma unroll
            for (int ot = 0; ot < 8; ++ot)
                out[(size_t)q * 128 + ot * 16 + l15] = acc[t][ot][jr] + bvec[ot * 16 + l15];
        }
    }
#undef STAGE
#undef SEXPR
#undef PVX
#undef Z4
}

extern "C" void kernel_launch(void* const* d_in, const int* in_sizes, int n_in,
                              void* d_out, int out_size, void* d_ws, size_t ws_size,
                              hipStream_t stream) {
    (void)in_sizes; (void)n_in; (void)out_size; (void)ws_size;
    const float* x       = (const float*)d_in[0];
    const float* centers = (const float*)d_in[1];
    const float* sigmas  = (const float*)d_in[2];
    const float* W       = (const float*)d_in[3];
    const float* b       = (const float*)d_in[4];
    float* out = (float*)d_out;

    char*  cfrag8 = (char*)d_ws;                     // 16384 slots * 16B = 256 KB
    short* wfrag  = (short*)(cfrag8 + 16384 * 16);   // 16384 slots * 16B = 256 KB
    float* nscsp  = (float*)(wfrag + 16384 * 8);     // 4 KB
    float* tsp    = nscsp + 1024;                    // 4 KB

    rbf_prep<<<384, 256, 0, stream>>>(centers, sigmas, W, cfrag8, wfrag, nscsp, tsp);
    rbf_main<<<512, 256, 0, stream>>>(x, b, cfrag8, wfrag, nscsp, tsp, out);
}

// Round 21
// 64.887 us; speedup vs baseline: 1.5050x; 1.1091x over previous
//
#include <hip/hip_runtime.h>

typedef __attribute__((ext_vector_type(8))) short bf16x8;
typedef __attribute__((ext_vector_type(4))) float f32x4;
typedef __attribute__((ext_vector_type(2))) long long2v;
typedef __attribute__((ext_vector_type(8))) int i32x8;
typedef unsigned int u32;
typedef unsigned long long u64;

#define LOG2E 1.44269504088896f

__device__ __forceinline__ short f2bf(float f) {
    union { float f; unsigned u; } v; v.f = f;
    unsigned r = v.u + 0x7fffu + ((v.u >> 16) & 1u);
    return (short)(r >> 16);
}

#if __has_builtin(__builtin_amdgcn_cvt_pk_fp8_f32)
// HW packed f32->fp8 (OCP e4m3fn on gfx950, RNE, saturating)
__device__ __forceinline__ long pack8_e4m3(float4 a, float4 b) {
    int lo = 0, hi = 0;
    lo = __builtin_amdgcn_cvt_pk_fp8_f32(a.x, a.y, lo, false);
    lo = __builtin_amdgcn_cvt_pk_fp8_f32(a.z, a.w, lo, true);
    hi = __builtin_amdgcn_cvt_pk_fp8_f32(b.x, b.y, hi, false);
    hi = __builtin_amdgcn_cvt_pk_fp8_f32(b.z, b.w, hi, true);
    return (long)(((u64)(u32)hi << 32) | (u32)lo);
}
#else
__device__ __forceinline__ u32 f2e4m3(float f) {
    u32 u = __float_as_uint(f);
    u32 sgn = (u >> 24) & 0x80u;
    u32 mag = u & 0x7fffffffu;
    if (mag >= 0x43E00000u) return sgn | 0x7Eu;
    if (mag < 0x3C800000u) {
        u32 q = (u32)(__uint_as_float(mag) * 512.0f + 0.5f);
        return sgn | q;
    }
    u32 r = mag + 0x0007FFFFu + ((mag >> 20) & 1u);
    u32 e8 = ((r >> 23) - 120u) & 0xFu;
    u32 m3 = (r >> 20) & 7u;
    return sgn | (e8 << 3) | m3;
}
__device__ __forceinline__ long pack8_e4m3(float4 a, float4 b) {
    u32 lo = f2e4m3(a.x) | (f2e4m3(a.y) << 8) | (f2e4m3(a.z) << 16) | (f2e4m3(a.w) << 24);
    u32 hi = f2e4m3(b.x) | (f2e4m3(b.y) << 8) | (f2e4m3(b.z) << 16) | (f2e4m3(b.w) << 24);
    return (long)(((u64)hi << 32) | lo);
}
#endif

#if __has_builtin(__builtin_amdgcn_exp2f)
#define EXP2(x) __builtin_amdgcn_exp2f(x)
#else
#define EXP2(x) __builtin_exp2f(x)
#endif

__device__ __forceinline__ u32 pack_bf16_trunc(float lo, float hi) {
#if __has_builtin(__builtin_amdgcn_perm)
    return __builtin_amdgcn_perm(__float_as_uint(hi), __float_as_uint(lo), 0x07060302u);
#else
    return (__float_as_uint(hi) & 0xFFFF0000u) | (__float_as_uint(lo) >> 16);
#endif
}

__device__ __forceinline__ void gload16(const void* g, void* l) {
    __builtin_amdgcn_global_load_lds(
        (const __attribute__((address_space(1))) void*)g,
        (__attribute__((address_space(3))) void*)l, 16, 0, 0);
}

// K=128 fp8 MFMA: scaled (identity e8m0 scales = 0x7F -> 2^0, layout-proof) with
// fallback to 4x K=32 on the SAME data (A/B k-conventions are self-consistent).
#if __has_builtin(__builtin_amdgcn_mfma_scale_f32_16x16x128_f8f6f4)
#define MFMA128(A, B, C) \
    C = __builtin_amdgcn_mfma_scale_f32_16x16x128_f8f6f4((A), (B), (C), 0, 0, 0, 0x7F7F7F7F, 0, 0x7F7F7F7F)
#else
#define MFMA128(A, B, C) do {                                                      \
        union { i32x8 v; long l[4]; } _a, _b; _a.v = (A); _b.v = (B);              \
        _Pragma("unroll")                                                          \
        for (int _dp = 0; _dp < 4; ++_dp)                                          \
            C = __builtin_amdgcn_mfma_f32_16x16x32_fp8_fp8(_a.l[_dp], _b.l[_dp], (C), 0, 0, 0); \
    } while (0)
#endif

// ---------------- prep (verbatim r17/r20 layouts; verified absmax 0.0) ----------------
// bid 0..255  : 2-fold tables, permuted slot ((c*2+h)*4+g)*4+j for center
//               m = c*32+8g+4h+j: nscs=-s*||c||^2*L, ts=2s*L
// bid 256..319: centers -> cfrag8 for K=128 operands (16B slots, r17 layout)
// bid 320..383: W -> wfrag (bf16) PV B-frag [c][ot][lane]
__global__ __launch_bounds__(256) void rbf_prep(
    const float* __restrict__ centers, const float* __restrict__ sigmas,
    const float* __restrict__ W,
    char* __restrict__ cfrag8, short* __restrict__ wfrag,
    float* __restrict__ nscsp, float* __restrict__ tsp)
{
    const int tid = threadIdx.x;
    const int bid = blockIdx.x;
    if (bid < 256) {
        const int lane = tid & 63, w = tid >> 6;
        const int m = bid * 4 + w;
        const float4 v = ((const float4*)(centers + (size_t)m * 256))[lane];
        float s = v.x*v.x + v.y*v.y + v.z*v.z + v.w*v.w;
        #pragma unroll
        for (int off = 32; off >= 1; off >>= 1) s += __shfl_xor(s, off, 64);
        if (lane == 0) {
            const float sg = sigmas[m];
            const int c = m >> 5, w5 = m & 31;
            const int g = w5 >> 3, r = w5 & 7, h = r >> 2, j = r & 3;
            const int slot = ((c * 2 + h) * 4 + g) * 4 + j;
            nscsp[slot] = -sg * s * LOG2E;
            tsp[slot]   = 2.0f * sg * LOG2E;
        }
    } else if (bid < 320) {
        const int s = (bid - 256) * 256 + tid;               // 0..16383 (16B slots)
        const int c = s >> 9, h2k = (s >> 7) & 3, piece = (s >> 6) & 1, lane = s & 63;
        const int h = h2k >> 1, ks = h2k & 1;
        const int l15 = lane & 15, g4 = lane >> 4;
        const int m = c * 32 + 8 * (l15 >> 2) + 4 * h + (l15 & 3);
        const int kb = ks * 128 + g4 * 32 + piece * 16;
        const float* cp = centers + (size_t)m * 256 + kb;
        const float4 a0 = *(const float4*)(cp);
        const float4 a1 = *(const float4*)(cp + 4);
        const float4 a2 = *(const float4*)(cp + 8);
        const float4 a3 = *(const float4*)(cp + 12);
        long2v t;
        t[0] = pack8_e4m3(a0, a1);
        t[1] = pack8_e4m3(a2, a3);
        *(long2v*)(cfrag8 + (size_t)s * 16) = t;
    } else {
        const int s = (bid - 320) * 256 + tid;               // 0..16383
        const int c = s >> 9, ot = (s >> 6) & 7, lane = s & 63;
        const int o = ot * 16 + (lane & 15);
        const int k = c * 32 + (lane >> 4) * 8;
        const float4 a = *(const float4*)(W + (size_t)o * 1024 + k);
        const float4 b = *(const float4*)(W + (size_t)o * 1024 + k + 4);
        bf16x8 t;
        t[0]=f2bf(a.x); t[1]=f2bf(a.y); t[2]=f2bf(a.z); t[3]=f2bf(a.w);
        t[4]=f2bf(b.x); t[5]=f2bf(b.y); t[6]=f2bf(b.z); t[7]=f2bf(b.w);
        ((bf16x8*)wfrag)[s] = t;
    }
}

// ---------------- main: ZERO intra-loop barriers — wave-private ring-2 LDS ----------------
// 512 blocks x 256 threads (4 fat waves, 32 rows/wave), 2 blocks/CU. Each wave
// owns a private 2x8KB LDS ring and stages its own A-chunks via global_load_lds;
// waves free-run across chunks (co-resident waves sit at different phases and
// fill each other's stalls). Hazards: (a) slot overwrite guarded by
// lgkmcnt(0)+sched_barrier after the A ds_reads, before the STAGE issue (same-
// wave program order); (b) DMA-completion guaranteed by in-order vmcnt — the
// compiler's W(c+1) wait retires STAGE(c+2) a full iteration before its reads.
// One __syncthreads total (prologue, for Tls).
__global__ __launch_bounds__(256, 2) void rbf_main(
    const float* __restrict__ x, const float* __restrict__ bvec,
    const char* __restrict__ cfrag8, const short* __restrict__ wfrag,
    const float* __restrict__ nscsp, const float* __restrict__ tsp,
    float* __restrict__ out)
{
    __shared__ char   Cb8[4][2][8192];  // [wave][ring-slot][8KB chunk] = 64 KB
    __shared__ float4 Tls[512];         // 8 KB: [0..255]=nscs, [256..511]=ts (permuted)

    const int tid = threadIdx.x;
    const int lane = tid & 63;
    const int l15 = lane & 15;
    const int g4 = lane >> 4;
    const int w = tid >> 6;                    // 0..3
    const int qb = blockIdx.x * 128 + w * 32;  // 32 rows per wave (2x 16-row tiles)

    // wave stages its WHOLE 8KB chunk into its own ring slot (8 x 1KB DMA)
#define STAGEW(ci, slot) do {                                                      \
        const char* _cs = cfrag8 + (size_t)(ci) * 8192 + lane * 16;                \
        _Pragma("unroll")                                                          \
        for (int _i = 0; _i < 8; ++_i)                                             \
            gload16(_cs + _i * 1024, &Cb8[w][(slot)][_i * 1024]);                  \
    } while (0)

#define Z4 (f32x4){0.f,0.f,0.f,0.f}

    // ---- prologue: stage chunks 0,1 into own ring; tables -> LDS; X -> fp8 ----
    STAGEW(0, 0);
    STAGEW(1, 1);

    Tls[tid]       = ((const float4*)nscsp)[tid];
    Tls[256 + tid] = ((const float4*)tsp)[tid];

    i32x8 xq00, xq01, xq10, xq11;   // [tile][kslice]
    float xs[2];
    #pragma unroll
    for (int t = 0; t < 2; ++t) {
        const float* xr = x + (size_t)(qb + t * 16 + l15) * 256;
        float ss = 0.f;
        #pragma unroll
        for (int ks = 0; ks < 2; ++ks) {
            union { long lg[4]; i32x8 v; } xx;
            const float* xb = xr + ks * 128 + g4 * 32;
            #pragma unroll
            for (int q8 = 0; q8 < 4; ++q8) {
                const float4 a = *(const float4*)(xb + q8 * 8);
                const float4 b = *(const float4*)(xb + q8 * 8 + 4);
                ss += a.x*a.x + a.y*a.y + a.z*a.z + a.w*a.w
                    + b.x*b.x + b.y*b.y + b.z*b.z + b.w*b.w;
                xx.lg[q8] = pack8_e4m3(a, b);
            }
            if (t == 0) { if (ks == 0) xq00 = xx.v; else xq01 = xx.v; }
            else        { if (ks == 0) xq10 = xx.v; else xq11 = xx.v; }
        }
        ss += __shfl_xor(ss, 16, 64);
        ss += __shfl_xor(ss, 32, 64);
        xs[t] = ss;
    }
    const float hxs0 = 0.5f * xs[0];
    const float hxs1 = 0.5f * xs[1];

    f32x4 acc[2][8];
    #pragma unroll
    for (int t = 0; t < 2; ++t)
        #pragma unroll
        for (int ot = 0; ot < 8; ++ot) acc[t][ot] = Z4;

    __syncthreads();   // the ONLY block barrier: Tls visibility + prologue DMA drain

    const bf16x8* wsrc = (const bf16x8*)wfrag + lane;

    for (int c = 0; c < 32; ++c) {
        const int slot = c & 1;

        // ---- W(c) -> regs (compiler's wait on these retires older STAGEs) ----
        bf16x8 wv[8];
        #pragma unroll
        for (int f = 0; f < 8; ++f) wv[f] = wsrc[(size_t)c * 512 + f * 64];

        // ---- A(c) -> regs from OWN ring slot ----
        const char* cb = &Cb8[w][slot][0] + (size_t)lane * 16;
        union { long2v p[2]; i32x8 v; } A0, A1, A2, A3;
        A0.p[0] = *(const long2v*)(cb);          A0.p[1] = *(const long2v*)(cb + 1024);
        A1.p[0] = *(const long2v*)(cb + 2048);   A1.p[1] = *(const long2v*)(cb + 3072);
        A2.p[0] = *(const long2v*)(cb + 4096);   A2.p[1] = *(const long2v*)(cb + 5120);
        A3.p[0] = *(const long2v*)(cb + 6144);   A3.p[1] = *(const long2v*)(cb + 7168);

        // fence: A fully in regs before this slot's overwrite can issue (rule #18)
        asm volatile("s_waitcnt lgkmcnt(0)" ::: "memory");
        __builtin_amdgcn_sched_barrier(0);

        // ---- stage chunk c+2 into the slot just freed (async, lands ~1 iter out) ----
        if (c <= 29) STAGEW(c + 2, slot);

        // ---- S: 8 scaled K=128 MFMAs (4 indep chains of 2) ----
        f32x4 s00 = Z4, s01 = Z4, s10 = Z4, s11 = Z4;
        MFMA128(A0.v, xq00, s00);  MFMA128(A0.v, xq10, s10);
        MFMA128(A1.v, xq01, s00);  MFMA128(A1.v, xq11, s10);
        MFMA128(A2.v, xq00, s01);  MFMA128(A2.v, xq10, s11);
        MFMA128(A3.v, xq01, s01);  MFMA128(A3.v, xq11, s11);

        // ---- phi = exp2(ts*(S - xs/2) + nscs); tables from LDS ----
        const int base0 = (c * 2 + 0) * 4 + g4;
        const int base1 = (c * 2 + 1) * 4 + g4;
        const float4 q0 = Tls[base0];
        const float4 t0 = Tls[256 + base0];
        const float4 q1 = Tls[base1];
        const float4 t1 = Tls[256 + base1];
        const float* q0p = (const float*)&q0; const float* t0p = (const float*)&t0;
        const float* q1p = (const float*)&q1; const float* t1p = (const float*)&t1;
        float p00[4], p01[4], p10[4], p11[4];
        #pragma unroll
        for (int j = 0; j < 4; ++j) {
            p00[j] = EXP2(fmaf(t0p[j], s00[j] - hxs0, q0p[j]));
            p01[j] = EXP2(fmaf(t1p[j], s01[j] - hxs0, q1p[j]));
            p10[j] = EXP2(fmaf(t0p[j], s10[j] - hxs1, q0p[j]));
            p11[j] = EXP2(fmaf(t1p[j], s11[j] - hxs1, q1p[j]));
        }
        union { u32 u[4]; bf16x8 v; } pa0, pa1;
        pa0.u[0] = pack_bf16_trunc(p00[0], p00[1]);
        pa0.u[1] = pack_bf16_trunc(p00[2], p00[3]);
        pa0.u[2] = pack_bf16_trunc(p01[0], p01[1]);
        pa0.u[3] = pack_bf16_trunc(p01[2], p01[3]);
        pa1.u[0] = pack_bf16_trunc(p10[0], p10[1]);
        pa1.u[1] = pack_bf16_trunc(p10[2], p10[3]);
        pa1.u[2] = pack_bf16_trunc(p11[0], p11[1]);
        pa1.u[3] = pack_bf16_trunc(p11[2], p11[3]);

        // ---- PV: 16 bf16 MFMAs ----
        #pragma unroll
        for (int ot = 0; ot < 8; ++ot) {
            acc[0][ot] = __builtin_amdgcn_mfma_f32_16x16x32_bf16(pa0.v, wv[ot], acc[0][ot], 0, 0, 0);
            acc[1][ot] = __builtin_amdgcn_mfma_f32_16x16x32_bf16(pa1.v, wv[ot], acc[1][ot], 0, 0, 0);
        }
        // no barrier, no explicit vmcnt: waves free-run
    }

    // ---- epilogue: D layout col=l15 (o-sub), row=g4*4+jr (q-sub) ----
    #pragma unroll
    for (int t = 0; t < 2; ++t) {
        #pragma unroll
        for (int jr = 0; jr < 4; ++jr) {
            const int q = qb + t * 16 + g4 * 4 + jr;
            #pragma unroll
            for (int ot = 0; ot < 8; ++ot)
                out[(size_t)q * 128 + ot * 16 + l15] = acc[t][ot][jr] + bvec[ot * 16 + l15];
        }
    }
#undef STAGEW
#undef Z4
}

extern "C" void kernel_launch(void* const* d_in, const int* in_sizes, int n_in,
                              void* d_out, int out_size, void* d_ws, size_t ws_size,
                              hipStream_t stream) {
    (void)in_sizes; (void)n_in; (void)out_size; (void)ws_size;
    const float* x       = (const float*)d_in[0];
    const float* centers = (const float*)d_in[1];
    const float* sigmas  = (const float*)d_in[2];
    const float* W       = (const float*)d_in[3];
    const float* b       = (const float*)d_in[4];
    float* out = (float*)d_out;

    char*  cfrag8 = (char*)d_ws;                     // 16384 slots * 16B = 256 KB
    short* wfrag  = (short*)(cfrag8 + 16384 * 16);   // 16384 slots * 16B = 256 KB
    float* nscsp  = (float*)(wfrag + 16384 * 8);     // 4 KB
    float* tsp    = nscsp + 1024;                    // 4 KB

    rbf_prep<<<384, 256, 0, stream>>>(centers, sigmas, W, cfrag8, wfrag, nscsp, tsp);
    rbf_main<<<512, 256, 0, stream>>>(x, b, cfrag8, wfrag, nscsp, tsp, out);
}